// Round 1
// baseline (115.358 us; speedup 1.0000x reference)
//
#include <hip/hip_runtime.h>
#include <math.h>

#define BB 4
#define SQL 512
#define SKL 512
#define HH 256
#define AA 128

// 2 * log2(e): Qt/Kt pre-scaled so the score loop feeds v_exp_f32 (2^x) directly.
#define PRESCALE 2.8853900817779268f
#define LOG2E    1.4426950408889634f

__device__ inline void fma4(float4& a, float s, const float4& b) {
    a.x = fmaf(s, b.x, a.x); a.y = fmaf(s, b.y, a.y);
    a.z = fmaf(s, b.z, a.z); a.w = fmaf(s, b.w, a.w);
}

// DPP add: x + dpp_move(x). Stays on the VALU pipe (no ds_swizzle / lgkm).
template <int CTRL>
__device__ __forceinline__ float dpp_add(float x) {
    int m = __builtin_amdgcn_update_dpp(__float_as_int(x), __float_as_int(x),
                                        CTRL, 0xF, 0xF, false);
    return x + __int_as_float(m);
}
// Sum over each aligned 8-lane group (ag = lane&7):
//   xor1 = quad_perm:[1,0,3,2] (0xB1), xor2 = quad_perm:[2,3,0,1] (0x4E),
//   xor4 = row_half_mirror (0x141; l -> l^7 within 8, valid after xor1/xor2).
__device__ __forceinline__ float red8(float x) {
    x = dpp_add<0xB1>(x);
    x = dpp_add<0x4E>(x);
    x = dpp_add<0x141>(x);
    return x;
}

// ---------------------------------------------------------------------------
// Kernel 1 "prep": Qt = PRESCALE*(Q@W_q), Kt = PRESCALE*(K@W_k), VW = V@W_o.
// (unchanged from verified version)
// ---------------------------------------------------------------------------
__global__ __launch_bounds__(256) void prep_kernel(
    const float* __restrict__ Q, const float* __restrict__ K,
    const float* __restrict__ V,
    const float* __restrict__ Wq, const float* __restrict__ Wk,
    const float* __restrict__ Wo,
    float* __restrict__ Qt, float* __restrict__ Kt, float* __restrict__ VW)
{
    __shared__ float rows[16 * HH];    // 16 KB
    __shared__ float wl[64 * 128];     // 32 KB
    int tid = threadIdx.x;
    int bid = blockIdx.x;

    const float* X; const float* W; float* Y;
    int ldW, ldY, col0, r0; float scale;
    if (bid < 128)      { X=Q; W=Wq; Y=Qt; ldW=AA; ldY=AA; col0=0; r0=bid*16;       scale=PRESCALE; }
    else if (bid < 256) { X=K; W=Wk; Y=Kt; ldW=AA; ldY=AA; col0=0; r0=(bid-128)*16; scale=PRESCALE; }
    else { int b2=bid-256; X=V; W=Wo; Y=VW; ldW=HH; ldY=HH; col0=(b2&1)*128; r0=(b2>>1)*16; scale=1.0f; }

    {
        const float4* Xv = (const float4*)(X + (size_t)r0 * HH);
        float4* rv = (float4*)rows;
        rv[tid]       = Xv[tid];
        rv[tid + 256] = Xv[tid + 256];
        rv[tid + 512] = Xv[tid + 512];
        rv[tid + 768] = Xv[tid + 768];
    }

    int r  = tid >> 5;
    int c4 = tid & 31;
    float4 accA = {0.f,0.f,0.f,0.f}, accB = {0.f,0.f,0.f,0.f};

    for (int ch = 0; ch < 4; ++ch) {
        __syncthreads();
        {
            const float* Wbase = W + (size_t)(ch * 64) * ldW + col0;
            float4* wv = (float4*)wl;
            #pragma unroll
            for (int it = 0; it < 8; ++it) {
                int l = tid + it * 256;
                wv[l] = *(const float4*)(Wbase + (size_t)(l >> 5) * ldW + ((l & 31) << 2));
            }
        }
        __syncthreads();
        const float* rrowA = rows + r * HH + ch * 64;
        const float* rrowB = rows + (r + 8) * HH + ch * 64;
        #pragma unroll 4
        for (int h4 = 0; h4 < 16; ++h4) {
            float4 ra = *(const float4*)(rrowA + h4 * 4);
            float4 rb = *(const float4*)(rrowB + h4 * 4);
            const float* wbase = wl + (h4 * 4) * 128 + (c4 << 2);
            float4 w0 = *(const float4*)(wbase);
            float4 w1 = *(const float4*)(wbase + 128);
            float4 w2 = *(const float4*)(wbase + 256);
            float4 w3 = *(const float4*)(wbase + 384);
            fma4(accA, ra.x, w0); fma4(accA, ra.y, w1);
            fma4(accA, ra.z, w2); fma4(accA, ra.w, w3);
            fma4(accB, rb.x, w0); fma4(accB, rb.y, w1);
            fma4(accB, rb.z, w2); fma4(accB, rb.w, w3);
        }
    }
    accA.x *= scale; accA.y *= scale; accA.z *= scale; accA.w *= scale;
    accB.x *= scale; accB.y *= scale; accB.z *= scale; accB.w *= scale;
    *(float4*)(Y + (size_t)(r0 + r)     * ldY + col0 + (c4 << 2)) = accA;
    *(float4*)(Y + (size_t)(r0 + r + 8) * ldY + col0 + (c4 << 2)) = accB;
}

// ---------------------------------------------------------------------------
// Kernel 2: fused scores + softmax + (weights @ VW + b_o).
// grid = B*SQ/4 = 512 blocks x 256 thr (4 waves). 4 q-rows per block.
//   score[q][k] = S_all - sum_a 2*v[a] * rcp(Ek*Eq + 1),  Ek=2^kt, Eq=2^qt.
// Eq is loop-invariant per thread (computed once) -> 1 exp2 per (k,a) shared
// by all 4 q-rows; per-element cost = 1 rcp + 2 fma.
// ag-reduction via DPP adds (VALU pipe), not ds_swizzle.
// kt register-double-buffered (prefetch next chunk during compute).
// Softmax: scores bounded by sum|2v| (~11.3) -> no max pass needed.
// Epilogue: wave w owns k-quarter [128w,128w+128); one VW pass serves 4 q.
// ---------------------------------------------------------------------------
__global__ __launch_bounds__(256, 3) void score_kernel(
    const float* __restrict__ Qt, const float* __restrict__ Kt,
    const float* __restrict__ v,  const float* __restrict__ VW,
    const float* __restrict__ bo,
    float* __restrict__ weights,  float* __restrict__ out)
{
    __shared__ float score[4][SKL];      // 8 KB
    __shared__ float pout[4][4][HH];     // 16 KB   (total 24 KB)

    int tid = threadIdx.x;
    int b  = blockIdx.x >> 7;            // 128 blocks per batch
    int q0 = (blockIdx.x & 127) << 2;    // 4 q-rows per block
    int ag = tid & 7;                    // a-range [16ag, 16ag+16)
    int kl = tid >> 3;                   // k within 32-chunk

    // register caches: Eq = 2^(Qt prescaled) for 4 q-rows, and 2*v fragment
    float Eq0[16], Eq1[16], Eq2[16], Eq3[16], v2[16];
    {
        const float4* vp  = (const float4*)(v + ag * 16);
        const float4* qp0 = (const float4*)(Qt + (size_t)(b * SQL + q0)     * AA + ag * 16);
        const float4* qp1 = (const float4*)(Qt + (size_t)(b * SQL + q0 + 1) * AA + ag * 16);
        const float4* qp2 = (const float4*)(Qt + (size_t)(b * SQL + q0 + 2) * AA + ag * 16);
        const float4* qp3 = (const float4*)(Qt + (size_t)(b * SQL + q0 + 3) * AA + ag * 16);
        #pragma unroll
        for (int j4 = 0; j4 < 4; ++j4) {
            float4 vv = vp[j4];
            v2[j4*4+0] = 2.0f*vv.x; v2[j4*4+1] = 2.0f*vv.y;
            v2[j4*4+2] = 2.0f*vv.z; v2[j4*4+3] = 2.0f*vv.w;
            float4 a0 = qp0[j4], a1 = qp1[j4], a2 = qp2[j4], a3 = qp3[j4];
            Eq0[j4*4+0] = __builtin_amdgcn_exp2f(a0.x); Eq0[j4*4+1] = __builtin_amdgcn_exp2f(a0.y);
            Eq0[j4*4+2] = __builtin_amdgcn_exp2f(a0.z); Eq0[j4*4+3] = __builtin_amdgcn_exp2f(a0.w);
            Eq1[j4*4+0] = __builtin_amdgcn_exp2f(a1.x); Eq1[j4*4+1] = __builtin_amdgcn_exp2f(a1.y);
            Eq1[j4*4+2] = __builtin_amdgcn_exp2f(a1.z); Eq1[j4*4+3] = __builtin_amdgcn_exp2f(a1.w);
            Eq2[j4*4+0] = __builtin_amdgcn_exp2f(a2.x); Eq2[j4*4+1] = __builtin_amdgcn_exp2f(a2.y);
            Eq2[j4*4+2] = __builtin_amdgcn_exp2f(a2.z); Eq2[j4*4+3] = __builtin_amdgcn_exp2f(a2.w);
            Eq3[j4*4+0] = __builtin_amdgcn_exp2f(a3.x); Eq3[j4*4+1] = __builtin_amdgcn_exp2f(a3.y);
            Eq3[j4*4+2] = __builtin_amdgcn_exp2f(a3.z); Eq3[j4*4+3] = __builtin_amdgcn_exp2f(a3.w);
        }
    }

    // S_all = sum_a v[a]
    float S_all;
    {
        float ls = 0.f;
        #pragma unroll
        for (int j = 0; j < 16; ++j) ls += v2[j];
        S_all = 0.5f * red8(ls);         // ls = 2*sum(v) over all 128 a
    }

    const float* KtB = Kt + (size_t)b * SKL * AA;

    auto loadk = [&](float* kt, int c) {
        const float4* kt4 = (const float4*)(KtB + (size_t)(c * 32 + kl) * AA + ag * 16);
        *(float4*)&kt[0]  = kt4[0];
        *(float4*)&kt[4]  = kt4[1];
        *(float4*)&kt[8]  = kt4[2];
        *(float4*)&kt[12] = kt4[3];
    };

    auto compute = [&](const float* kt, int c) {
        float p0 = 0.f, p1 = 0.f, p2 = 0.f, p3 = 0.f;
        #pragma unroll
        for (int j = 0; j < 16; ++j) {
            float Ek = __builtin_amdgcn_exp2f(kt[j]);
            float r0 = __builtin_amdgcn_rcpf(fmaf(Ek, Eq0[j], 1.0f));
            float r1 = __builtin_amdgcn_rcpf(fmaf(Ek, Eq1[j], 1.0f));
            float r2 = __builtin_amdgcn_rcpf(fmaf(Ek, Eq2[j], 1.0f));
            float r3 = __builtin_amdgcn_rcpf(fmaf(Ek, Eq3[j], 1.0f));
            p0 = fmaf(v2[j], r0, p0);
            p1 = fmaf(v2[j], r1, p1);
            p2 = fmaf(v2[j], r2, p2);
            p3 = fmaf(v2[j], r3, p3);
        }
        p0 = red8(p0); p1 = red8(p1); p2 = red8(p2); p3 = red8(p3);
        if (ag == 0) {
            int k = c * 32 + kl;
            score[0][k] = (S_all - p0) * LOG2E;
            score[1][k] = (S_all - p1) * LOG2E;
            score[2][k] = (S_all - p2) * LOG2E;
            score[3][k] = (S_all - p3) * LOG2E;
        }
    };

    // ---- main loop: 16 chunks x 32 k-rows, register ping-pong on kt ----
    {
        float ktA[16], ktB_[16];
        loadk(ktA, 0);
        #pragma unroll 1
        for (int cc = 0; cc < 8; ++cc) {
            int c0 = cc * 2;
            loadk(ktB_, c0 + 1);
            compute(ktA, c0);
            if (cc != 7) loadk(ktA, c0 + 2);
            compute(ktB_, c0 + 1);
        }
    }
    __syncthreads();

    // ---- softmax (no max pass: |score| bounded by sum|2v|) ----
    int wave = tid >> 6, lane = tid & 63;
    {
        int qi = wave;                   // 4 waves, one q-row each
        float ssum = 0.f;
        #pragma unroll
        for (int it = 0; it < 2; ++it) {
            int k0 = it * 256 + (lane << 2);
            float4 sv = *(float4*)&score[qi][k0];
            sv.x = __builtin_amdgcn_exp2f(sv.x);
            sv.y = __builtin_amdgcn_exp2f(sv.y);
            sv.z = __builtin_amdgcn_exp2f(sv.z);
            sv.w = __builtin_amdgcn_exp2f(sv.w);
            *(float4*)&score[qi][k0] = sv;
            ssum += (sv.x + sv.y) + (sv.z + sv.w);
        }
        #pragma unroll
        for (int off = 32; off; off >>= 1) ssum += __shfl_xor(ssum, off);
        float rinv = 1.0f / ssum;
        size_t rowoff = (size_t)(b * SQL + q0 + qi) * SKL;
        #pragma unroll
        for (int it = 0; it < 2; ++it) {
            int k0 = it * 256 + (lane << 2);
            float4 sv = *(float4*)&score[qi][k0];
            sv.x *= rinv; sv.y *= rinv; sv.z *= rinv; sv.w *= rinv;
            *(float4*)&score[qi][k0] = sv;
            *(float4*)(weights + rowoff + k0) = sv;
        }
    }
    __syncthreads();

    // ---- epilogue: wave w owns k in [128w, 128w+128); one VW read serves 4 q
    {
        const float4* VWb = (const float4*)(VW + (size_t)b * SKL * HH);
        float4 a0 = {0,0,0,0}, a1 = {0,0,0,0}, a2 = {0,0,0,0}, a3 = {0,0,0,0};
        int kbase = wave * 128;
        #pragma unroll 2
        for (int k4 = 0; k4 < 32; ++k4) {
            int kk = kbase + k4 * 4;
            float4 w0 = *(const float4*)&score[0][kk];   // wave-uniform broadcast
            float4 w1 = *(const float4*)&score[1][kk];
            float4 w2 = *(const float4*)&score[2][kk];
            float4 w3 = *(const float4*)&score[3][kk];
            float4 vw;
            vw = VWb[(size_t)(kk + 0) * (HH/4) + lane];
            fma4(a0, w0.x, vw); fma4(a1, w1.x, vw); fma4(a2, w2.x, vw); fma4(a3, w3.x, vw);
            vw = VWb[(size_t)(kk + 1) * (HH/4) + lane];
            fma4(a0, w0.y, vw); fma4(a1, w1.y, vw); fma4(a2, w2.y, vw); fma4(a3, w3.y, vw);
            vw = VWb[(size_t)(kk + 2) * (HH/4) + lane];
            fma4(a0, w0.z, vw); fma4(a1, w1.z, vw); fma4(a2, w2.z, vw); fma4(a3, w3.z, vw);
            vw = VWb[(size_t)(kk + 3) * (HH/4) + lane];
            fma4(a0, w0.w, vw); fma4(a1, w1.w, vw); fma4(a2, w2.w, vw); fma4(a3, w3.w, vw);
        }
        *(float4*)&pout[wave][0][lane << 2] = a0;
        *(float4*)&pout[wave][1][lane << 2] = a1;
        *(float4*)&pout[wave][2][lane << 2] = a2;
        *(float4*)&pout[wave][3][lane << 2] = a3;
    }
    __syncthreads();
    {
        int h = tid;
        float bias = bo[h];
        #pragma unroll
        for (int qi = 0; qi < 4; ++qi) {
            float s = bias + pout[0][qi][h] + pout[1][qi][h]
                           + pout[2][qi][h] + pout[3][qi][h];
            out[(size_t)(b * SQL + q0 + qi) * HH + h] = s;
        }
    }
}

// ---------------------------------------------------------------------------
extern "C" void kernel_launch(void* const* d_in, const int* in_sizes, int n_in,
                              void* d_out, int out_size, void* d_ws, size_t ws_size,
                              hipStream_t stream)
{
    const float* Q  = (const float*)d_in[0];
    const float* K  = (const float*)d_in[1];
    const float* V  = (const float*)d_in[2];
    const float* Wq = (const float*)d_in[3];
    const float* Wk = (const float*)d_in[4];
    const float* v  = (const float*)d_in[5];
    const float* Wo = (const float*)d_in[6];
    const float* bo = (const float*)d_in[7];

    float* out     = (float*)d_out;                   // (B,SQ,H) = 524288
    float* weights = out + (size_t)BB * SQL * HH;     // (B,SQ,SK) = 1048576

    float* Qt = (float*)d_ws;                         // 262144 floats
    float* Kt = Qt + (size_t)BB * SQL * AA;           // 262144 floats
    float* VW = Kt + (size_t)BB * SKL * AA;           // 524288 floats

    prep_kernel <<<512, 256, 0, stream>>>(Q, K, V, Wq, Wk, Wo, Qt, Kt, VW);
    score_kernel<<<512, 256, 0, stream>>>(Qt, Kt, v, VW, bo, weights, out);
}

// Round 2
// 114.251 us; speedup vs baseline: 1.0097x; 1.0097x over previous
//
#include <hip/hip_runtime.h>
#include <math.h>

#define BB 4
#define SQL 512
#define SKL 512
#define HH 256
#define AA 128

// 2 * log2(e): Qt/Kt pre-scaled so the score loop feeds v_exp_f32 (2^x) directly.
#define PRESCALE 2.8853900817779268f
#define LOG2E    1.4426950408889634f

__device__ inline void fma4(float4& a, float s, const float4& b) {
    a.x = fmaf(s, b.x, a.x); a.y = fmaf(s, b.y, a.y);
    a.z = fmaf(s, b.z, a.z); a.w = fmaf(s, b.w, a.w);
}

// DPP add: x + dpp_move(x). Stays on the VALU pipe (no ds_swizzle / lgkm).
template <int CTRL>
__device__ __forceinline__ float dpp_add(float x) {
    int m = __builtin_amdgcn_update_dpp(__float_as_int(x), __float_as_int(x),
                                        CTRL, 0xF, 0xF, false);
    return x + __int_as_float(m);
}
// Sum over each aligned 8-lane group (ag = lane&7):
//   xor1 = quad_perm:[1,0,3,2] (0xB1), xor2 = quad_perm:[2,3,0,1] (0x4E),
//   xor4 = row_half_mirror (0x141).
__device__ __forceinline__ float red8(float x) {
    x = dpp_add<0xB1>(x);
    x = dpp_add<0x4E>(x);
    x = dpp_add<0x141>(x);
    return x;
}

// ---------------------------------------------------------------------------
// Kernel 1 "prep": Qt = PRESCALE*(Q@W_q), Kt = PRESCALE*(K@W_k), VW = V@W_o.
// (unchanged from verified version)
// ---------------------------------------------------------------------------
__global__ __launch_bounds__(256) void prep_kernel(
    const float* __restrict__ Q, const float* __restrict__ K,
    const float* __restrict__ V,
    const float* __restrict__ Wq, const float* __restrict__ Wk,
    const float* __restrict__ Wo,
    float* __restrict__ Qt, float* __restrict__ Kt, float* __restrict__ VW)
{
    __shared__ float rows[16 * HH];    // 16 KB
    __shared__ float wl[64 * 128];     // 32 KB
    int tid = threadIdx.x;
    int bid = blockIdx.x;

    const float* X; const float* W; float* Y;
    int ldW, ldY, col0, r0; float scale;
    if (bid < 128)      { X=Q; W=Wq; Y=Qt; ldW=AA; ldY=AA; col0=0; r0=bid*16;       scale=PRESCALE; }
    else if (bid < 256) { X=K; W=Wk; Y=Kt; ldW=AA; ldY=AA; col0=0; r0=(bid-128)*16; scale=PRESCALE; }
    else { int b2=bid-256; X=V; W=Wo; Y=VW; ldW=HH; ldY=HH; col0=(b2&1)*128; r0=(b2>>1)*16; scale=1.0f; }

    {
        const float4* Xv = (const float4*)(X + (size_t)r0 * HH);
        float4* rv = (float4*)rows;
        rv[tid]       = Xv[tid];
        rv[tid + 256] = Xv[tid + 256];
        rv[tid + 512] = Xv[tid + 512];
        rv[tid + 768] = Xv[tid + 768];
    }

    int r  = tid >> 5;
    int c4 = tid & 31;
    float4 accA = {0.f,0.f,0.f,0.f}, accB = {0.f,0.f,0.f,0.f};

    for (int ch = 0; ch < 4; ++ch) {
        __syncthreads();
        {
            const float* Wbase = W + (size_t)(ch * 64) * ldW + col0;
            float4* wv = (float4*)wl;
            #pragma unroll
            for (int it = 0; it < 8; ++it) {
                int l = tid + it * 256;
                wv[l] = *(const float4*)(Wbase + (size_t)(l >> 5) * ldW + ((l & 31) << 2));
            }
        }
        __syncthreads();
        const float* rrowA = rows + r * HH + ch * 64;
        const float* rrowB = rows + (r + 8) * HH + ch * 64;
        #pragma unroll 4
        for (int h4 = 0; h4 < 16; ++h4) {
            float4 ra = *(const float4*)(rrowA + h4 * 4);
            float4 rb = *(const float4*)(rrowB + h4 * 4);
            const float* wbase = wl + (h4 * 4) * 128 + (c4 << 2);
            float4 w0 = *(const float4*)(wbase);
            float4 w1 = *(const float4*)(wbase + 128);
            float4 w2 = *(const float4*)(wbase + 256);
            float4 w3 = *(const float4*)(wbase + 384);
            fma4(accA, ra.x, w0); fma4(accA, ra.y, w1);
            fma4(accA, ra.z, w2); fma4(accA, ra.w, w3);
            fma4(accB, rb.x, w0); fma4(accB, rb.y, w1);
            fma4(accB, rb.z, w2); fma4(accB, rb.w, w3);
        }
    }
    accA.x *= scale; accA.y *= scale; accA.z *= scale; accA.w *= scale;
    accB.x *= scale; accB.y *= scale; accB.z *= scale; accB.w *= scale;
    *(float4*)(Y + (size_t)(r0 + r)     * ldY + col0 + (c4 << 2)) = accA;
    *(float4*)(Y + (size_t)(r0 + r + 8) * ldY + col0 + (c4 << 2)) = accB;
}

// ---------------------------------------------------------------------------
// Kernel 2: fused scores + softmax + (weights @ VW + b_o).
// grid = B*SQ/8 = 256 blocks x 512 thr (8 waves). 8 q-rows per block.
//   score[q][k] = S_all - sum_a 2*v[a] * rcp(Ek*Eq + 1),  Ek=2^kt, Eq=2^qt.
// 8 q-rows amortize: exp2(kt) once per (k,a) for 8 rows; Kt read once per
// 8 rows (128 MB total); VW epilogue pass once per 8 rows (128 MB total —
// half of the 4-row version; epilogue was L2-BW-bound at 256 MB).
// VGPR: Eq[8][16]=128 + kt dbuf 32 + v2 16 + misc ~= 210; capped at 256 by
// __launch_bounds__(512,2) -> 1 block/CU, 2 waves/SIMD (trans/VALU overlap).
// Epilogue: wave w owns k in [64w, 64w+64); LDS tree in 2 rounds (pout 32KB).
// ---------------------------------------------------------------------------
__global__ __launch_bounds__(512, 2) void score_kernel(
    const float* __restrict__ Qt, const float* __restrict__ Kt,
    const float* __restrict__ v,  const float* __restrict__ VW,
    const float* __restrict__ bo,
    float* __restrict__ weights,  float* __restrict__ out)
{
    __shared__ float score[8][SKL];      // 16 KB
    __shared__ float pout[8][4][HH];     // 32 KB   (total 48 KB)

    int tid = threadIdx.x;
    int b  = blockIdx.x >> 6;            // 64 blocks per batch
    int q0 = (blockIdx.x & 63) << 3;     // 8 q-rows per block
    int ag = tid & 7;                    // a-range [16ag, 16ag+16)
    int kl = tid >> 3;                   // k within 64-chunk (0..63)

    // register caches: Eq = 2^(Qt prescaled) for 8 q-rows, and 2*v fragment
    float Eq[8][16], v2[16];
    {
        const float4* vp = (const float4*)(v + ag * 16);
        #pragma unroll
        for (int j4 = 0; j4 < 4; ++j4) {
            float4 vv = vp[j4];
            v2[j4*4+0] = 2.0f*vv.x; v2[j4*4+1] = 2.0f*vv.y;
            v2[j4*4+2] = 2.0f*vv.z; v2[j4*4+3] = 2.0f*vv.w;
        }
        #pragma unroll
        for (int q = 0; q < 8; ++q) {
            const float4* qp = (const float4*)(Qt + (size_t)(b * SQL + q0 + q) * AA + ag * 16);
            #pragma unroll
            for (int j4 = 0; j4 < 4; ++j4) {
                float4 a = qp[j4];
                Eq[q][j4*4+0] = __builtin_amdgcn_exp2f(a.x);
                Eq[q][j4*4+1] = __builtin_amdgcn_exp2f(a.y);
                Eq[q][j4*4+2] = __builtin_amdgcn_exp2f(a.z);
                Eq[q][j4*4+3] = __builtin_amdgcn_exp2f(a.w);
            }
        }
    }

    // S_all = sum_a v[a]
    float S_all;
    {
        float ls = 0.f;
        #pragma unroll
        for (int j = 0; j < 16; ++j) ls += v2[j];
        S_all = 0.5f * red8(ls);         // ls = 2*sum(v) over all 128 a
    }

    const float* KtB = Kt + (size_t)b * SKL * AA;

    auto loadk = [&](float* kt, int c) {
        const float4* kt4 = (const float4*)(KtB + (size_t)(c * 64 + kl) * AA + ag * 16);
        *(float4*)&kt[0]  = kt4[0];
        *(float4*)&kt[4]  = kt4[1];
        *(float4*)&kt[8]  = kt4[2];
        *(float4*)&kt[12] = kt4[3];
    };

    auto compute = [&](const float* kt, int c) {
        float p[8];
        #pragma unroll
        for (int q = 0; q < 8; ++q) p[q] = 0.f;
        #pragma unroll
        for (int j = 0; j < 16; ++j) {
            float Ek = __builtin_amdgcn_exp2f(kt[j]);
            float vj = v2[j];
            #pragma unroll
            for (int q = 0; q < 8; ++q) {
                float r = __builtin_amdgcn_rcpf(fmaf(Ek, Eq[q][j], 1.0f));
                p[q] = fmaf(vj, r, p[q]);
            }
        }
        #pragma unroll
        for (int q = 0; q < 8; ++q) p[q] = red8(p[q]);
        if (ag == 0) {
            int k = c * 64 + kl;
            #pragma unroll
            for (int q = 0; q < 8; ++q)
                score[q][k] = (S_all - p[q]) * LOG2E;
        }
    };

    // ---- main loop: 8 chunks x 64 k-rows, register ping-pong on kt ----
    {
        float ktA[16], ktB_[16];
        loadk(ktA, 0);
        #pragma unroll 1
        for (int cc = 0; cc < 4; ++cc) {
            int c0 = cc * 2;
            loadk(ktB_, c0 + 1);
            compute(ktA, c0);
            if (cc != 3) loadk(ktA, c0 + 2);
            compute(ktB_, c0 + 1);
        }
    }
    __syncthreads();

    // ---- softmax (no max pass: |score| bounded by sum|2v| ~ 11.3 nat) ----
    int wave = tid >> 6, lane = tid & 63;
    {
        int qi = wave;                   // 8 waves, one q-row each
        float ssum = 0.f;
        #pragma unroll
        for (int it = 0; it < 2; ++it) {
            int k0 = it * 256 + (lane << 2);
            float4 sv = *(float4*)&score[qi][k0];
            sv.x = __builtin_amdgcn_exp2f(sv.x);
            sv.y = __builtin_amdgcn_exp2f(sv.y);
            sv.z = __builtin_amdgcn_exp2f(sv.z);
            sv.w = __builtin_amdgcn_exp2f(sv.w);
            *(float4*)&score[qi][k0] = sv;
            ssum += (sv.x + sv.y) + (sv.z + sv.w);
        }
        #pragma unroll
        for (int off = 32; off; off >>= 1) ssum += __shfl_xor(ssum, off);
        float rinv = 1.0f / ssum;
        size_t rowoff = (size_t)(b * SQL + q0 + qi) * SKL;
        #pragma unroll
        for (int it = 0; it < 2; ++it) {
            int k0 = it * 256 + (lane << 2);
            float4 sv = *(float4*)&score[qi][k0];
            sv.x *= rinv; sv.y *= rinv; sv.z *= rinv; sv.w *= rinv;
            *(float4*)&score[qi][k0] = sv;
            *(float4*)(weights + rowoff + k0) = sv;
        }
    }
    __syncthreads();

    // ---- epilogue: wave w owns k in [64w, 64w+64); one VW pass serves 8 q
    float4 acc[8];
    {
        #pragma unroll
        for (int q = 0; q < 8; ++q) acc[q] = make_float4(0.f, 0.f, 0.f, 0.f);
        const float4* VWb = (const float4*)(VW + (size_t)b * SKL * HH);
        int kbase = wave * 64;
        #pragma unroll 2
        for (int k4 = 0; k4 < 16; ++k4) {
            int kk = kbase + k4 * 4;
            float4 w[8];
            #pragma unroll
            for (int q = 0; q < 8; ++q) w[q] = *(const float4*)&score[q][kk];  // uniform -> broadcast
            float4 vw;
            vw = VWb[(size_t)(kk + 0) * (HH/4) + lane];
            #pragma unroll
            for (int q = 0; q < 8; ++q) fma4(acc[q], w[q].x, vw);
            vw = VWb[(size_t)(kk + 1) * (HH/4) + lane];
            #pragma unroll
            for (int q = 0; q < 8; ++q) fma4(acc[q], w[q].y, vw);
            vw = VWb[(size_t)(kk + 2) * (HH/4) + lane];
            #pragma unroll
            for (int q = 0; q < 8; ++q) fma4(acc[q], w[q].z, vw);
            vw = VWb[(size_t)(kk + 3) * (HH/4) + lane];
            #pragma unroll
            for (int q = 0; q < 8; ++q) fma4(acc[q], w[q].w, vw);
        }
    }

    // ---- LDS tree-reduce over the 8 waves, 2 rounds of 4 q-rows ----
    int h  = tid & 255;
    int qh = tid >> 8;                   // 0 or 1
    float bias = bo[h];
    #pragma unroll
    for (int rnd = 0; rnd < 2; ++rnd) {
        #pragma unroll
        for (int q = 0; q < 4; ++q)
            *(float4*)&pout[wave][q][lane << 2] = acc[rnd * 4 + q];
        __syncthreads();
        #pragma unroll
        for (int qq = 0; qq < 2; ++qq) {
            int qi = qh * 2 + qq;        // 0..3 within round
            float s = bias;
            #pragma unroll
            for (int w2 = 0; w2 < 8; ++w2) s += pout[w2][qi][h];
            out[(size_t)(b * SQL + q0 + rnd * 4 + qi) * HH + h] = s;
        }
        __syncthreads();
    }
}

// ---------------------------------------------------------------------------
extern "C" void kernel_launch(void* const* d_in, const int* in_sizes, int n_in,
                              void* d_out, int out_size, void* d_ws, size_t ws_size,
                              hipStream_t stream)
{
    const float* Q  = (const float*)d_in[0];
    const float* K  = (const float*)d_in[1];
    const float* V  = (const float*)d_in[2];
    const float* Wq = (const float*)d_in[3];
    const float* Wk = (const float*)d_in[4];
    const float* v  = (const float*)d_in[5];
    const float* Wo = (const float*)d_in[6];
    const float* bo = (const float*)d_in[7];

    float* out     = (float*)d_out;                   // (B,SQ,H) = 524288
    float* weights = out + (size_t)BB * SQL * HH;     // (B,SQ,SK) = 1048576

    float* Qt = (float*)d_ws;                         // 262144 floats
    float* Kt = Qt + (size_t)BB * SQL * AA;           // 262144 floats
    float* VW = Kt + (size_t)BB * SKL * AA;           // 524288 floats

    prep_kernel <<<512, 256, 0, stream>>>(Q, K, V, Wq, Wk, Wo, Qt, Kt, VW);
    score_kernel<<<256, 512, 0, stream>>>(Qt, Kt, v, VW, bo, weights, out);
}